// Round 3
// baseline (565.846 us; speedup 1.0000x reference)
//
#include <hip/hip_runtime.h>
#include <cstdint>
#include <cstddef>

// B=1024 tokens, D=1024, E=16 experts, H=2048, O=1024, top-4 routing.
typedef __bf16 bh;
typedef bh bh8 __attribute__((ext_vector_type(8)));
typedef bh bh4 __attribute__((ext_vector_type(4)));
typedef float fx4 __attribute__((ext_vector_type(4)));

__device__ __forceinline__ void gload16(const void* g, void* l) {
  __builtin_amdgcn_global_load_lds(
      (const __attribute__((address_space(1))) void*)g,
      (__attribute__((address_space(3))) void*)l, 16, 0, 0);
}

// LDS slot s of row r holds global 16B-chunk s^swz(r) (writer & reader agree).
__device__ __forceinline__ int swz(int r) { return (r >> 1) & 3; }

// ---------------- gating: one block per token ----------------
__global__ __launch_bounds__(256) void k_gating(
    const float* __restrict__ x, const float* __restrict__ wg,
    const float* __restrict__ wn, const float* __restrict__ nz,
    bh* __restrict__ xbf, unsigned* __restrict__ cnt,
    int* __restrict__ tok_buck, float* __restrict__ gate_buck,
    float* __restrict__ imp_part, float* __restrict__ load_part) {
  const int b = blockIdx.x, tid = threadIdx.x;
  __shared__ __align__(16) float xs[1024];
  __shared__ float part[32][9];
  __shared__ float vals[32];
  fx4 v = *(const fx4*)(x + (size_t)b * 1024 + tid * 4);
  *(fx4*)(xs + tid * 4) = v;
  bh4 xb;
#pragma unroll
  for (int u = 0; u < 4; ++u) xb[u] = (bh)v[u];
  *(bh4*)(xbf + (size_t)b * 1024 + tid * 4) = xb;
  __syncthreads();
  const int col = tid & 31, g = tid >> 5;
  const float* wp = ((col < 16) ? wg : wn) + (col & 15);
  float s = 0.f;
  for (int it = g * 128; it < g * 128 + 128; ++it) s += xs[it] * wp[it * 16];
  part[col][g] = s;
  __syncthreads();
  if (tid < 32) {
    float tsum = 0.f;
#pragma unroll
    for (int gg = 0; gg < 8; ++gg) tsum += part[tid][gg];
    vals[tid] = tsum;
  }
  __syncthreads();
  if (tid == 0) {
    float clean[16], sd[16], noisy[16];
#pragma unroll
    for (int e = 0; e < 16; ++e) {
      clean[e] = vals[e];
      float raw = vals[16 + e];
      float sp = fmaxf(raw, 0.f) + log1pf(expf(-fabsf(raw)));
      sd[e] = sp + 0.1f;
      noisy[e] = clean[e] + nz[b * 16 + e] * sd[e];
    }
    float tv[5]; int ti[5]; unsigned used = 0;
    for (int r = 0; r < 5; ++r) {
      float bst = -INFINITY; int bi = 0;
      for (int e = 0; e < 16; ++e)
        if (!((used >> e) & 1u) && noisy[e] > bst) { bst = noisy[e]; bi = e; }
      used |= 1u << bi; tv[r] = bst; ti[r] = bi;
    }
    float gts[4]; float se = 0.f;
#pragma unroll
    for (int k = 0; k < 4; ++k) { gts[k] = expf(tv[k] - tv[0]); se += gts[k]; }
#pragma unroll
    for (int k = 0; k < 4; ++k) gts[k] /= se;
    const float thr_in = tv[4], thr_out = tv[3];
    float imp[16];
#pragma unroll
    for (int e = 0; e < 16; ++e) imp[e] = 0.f;
    for (int k = 0; k < 4; ++k) imp[ti[k]] = gts[k];
    for (int e = 0; e < 16; ++e) imp_part[b * 16 + e] = imp[e];
    for (int e = 0; e < 16; ++e) {
      bool is_in = noisy[e] > thr_in;
      float z = (clean[e] - (is_in ? thr_in : thr_out)) / sd[e];
      load_part[b * 16 + e] = 0.5f * (1.f + erff(z * 0.70710678118654752f));
    }
    for (int k = 0; k < 4; ++k) {
      int ee = ti[k];
      unsigned p = atomicAdd(&cnt[ee], 1u);
      tok_buck[ee * 1024 + (int)p] = b;
      gate_buck[ee * 1024 + (int)p] = gts[k];
    }
  }
}

__device__ __forceinline__ float cv2_16(const float* v) {
  float m = 0.f;
  for (int i = 0; i < 16; ++i) m += v[i];
  m *= (1.f / 16.f);
  float var = 0.f;
  for (int i = 0; i < 16; ++i) { float d = v[i] - m; var += d * d; }
  var *= (1.f / 15.f);
  return var / (m * m + 1e-10f);
}

// ---------------- offsets + loss ----------------
__global__ __launch_bounds__(256) void k_finalize(
    const unsigned* __restrict__ cnt, unsigned* __restrict__ offs,
    const float* __restrict__ imp_part, const float* __restrict__ load_part,
    float* __restrict__ loss_out) {
  const int tid = threadIdx.x;
  __shared__ float red[256];
  __shared__ float impv[16], loadv[16];
  const int e = tid & 15, p = tid >> 4;
  float s = 0.f;
  for (int r = 0; r < 64; ++r) s += imp_part[((p * 64 + r) << 4) + e];
  red[tid] = s;
  __syncthreads();
  if (tid < 16) {
    float t = 0.f;
    for (int pp = 0; pp < 16; ++pp) t += red[pp * 16 + tid];
    impv[tid] = t;
  }
  __syncthreads();
  s = 0.f;
  for (int r = 0; r < 64; ++r) s += load_part[((p * 64 + r) << 4) + e];
  red[tid] = s;
  __syncthreads();
  if (tid < 16) {
    float t = 0.f;
    for (int pp = 0; pp < 16; ++pp) t += red[pp * 16 + tid];
    loadv[tid] = t;
  }
  __syncthreads();
  if (tid == 0) {
    unsigned o = 0;
    for (int ee = 0; ee < 16; ++ee) { offs[ee] = o; o += cnt[ee]; }
    loss_out[0] = (cv2_16(impv) + cv2_16(loadv)) * 1e-4f;
  }
}

// ---------------- GEMM1: h = relu(x @ W1[e] + b1[e]) ----------------
// M-tile 128 (mt-split), N-tile 64, BK=32, single-barrier dbuf pipeline.
__global__ __launch_bounds__(256, 2) void k_gemm1p(
    const bh* __restrict__ xbf, const float* __restrict__ W1,
    const float* __restrict__ b1, const int* __restrict__ tok_buck,
    const unsigned* __restrict__ cnt, const unsigned* __restrict__ offs,
    bh* __restrict__ hbf) {
  const int e = blockIdx.z, mt = blockIdx.y, nt = blockIdx.x;
  const int ne = (int)cnt[e];
  if (mt * 128 >= ne) return;
  __shared__ __align__(16) bh As[2][128 * 32];  // 2 x 8 KB
  __shared__ __align__(16) bh Bs[2][64 * 32];   // 2 x 4 KB
  const int tid = threadIdx.x;
  const int lane = tid & 63, wv = tid >> 6;
  const int NK = 32;  // K=1024 / 32

  // ---- A gather addresses (2 gload insts/thread) ----
  const bh* a_src[2]; int a_dsto[2];
#pragma unroll
  for (int r = 0; r < 2; ++r) {
    int task = r * 256 + tid;
    int row = task >> 2, s = task & 3;
    int gm = mt * 128 + row; if (gm >= ne) gm = ne - 1;
    int tok = tok_buck[e * 1024 + gm];
    a_src[r] = xbf + (size_t)tok * 1024 + ((s ^ swz(row)) << 3);
    a_dsto[r] = (r * 256 + (wv << 6)) * 16;  // byte offset in buffer
  }
  // ---- B source: thread covers n = nt*64+(tid&63), k-quarter kq ----
  const int nl = tid & 63, kq = tid >> 6;  // kq 0..3
  const float* bp = W1 + (size_t)e * (1024 * 2048) + (size_t)(kq * 8) * 2048 +
                    nt * 64 + nl;
  const int b_wro = nl * 32 + ((kq ^ swz(nl)) << 3);  // bh offset in buffer

  const int ln15 = lane & 15, q = lane >> 4;
  int a_off[2], b_off[4];
#pragma unroll
  for (int i = 0; i < 2; ++i) {
    int row = wv * 32 + i * 16 + ln15;
    a_off[i] = row * 32 + ((q ^ swz(row)) << 3);
  }
#pragma unroll
  for (int j = 0; j < 4; ++j) {
    int row = j * 16 + ln15;
    b_off[j] = row * 32 + ((q ^ swz(row)) << 3);
  }
  fx4 zero = {0.f, 0.f, 0.f, 0.f};
  fx4 acc[2][4];
#pragma unroll
  for (int i = 0; i < 2; ++i)
#pragma unroll
    for (int j = 0; j < 4; ++j) acc[i][j] = zero;

  float rb[2][8];
  // ---- prolog ----
#pragma unroll
  for (int i = 0; i < 8; ++i) rb[0][i] = bp[(size_t)i * 2048];
#pragma unroll
  for (int r = 0; r < 2; ++r) gload16(a_src[r], (char*)As[0] + a_dsto[r]);
  {
    bh8 w;
#pragma unroll
    for (int u = 0; u < 8; ++u) w[u] = (bh)rb[0][u];
    *(bh8*)(Bs[0] + b_wro) = w;
  }
#pragma unroll
  for (int i = 0; i < 8; ++i) rb[1][i] = bp[(size_t)(32 + i) * 2048];
#pragma unroll
  for (int r = 0; r < 2; ++r) gload16(a_src[r] + 32, (char*)As[1] + a_dsto[r]);
  __syncthreads();

  for (int kt = 0; kt < NK; ++kt) {
    const int p = kt & 1;
    // MFMA on buf p
    bh8 bfr[4], af[2];
#pragma unroll
    for (int j = 0; j < 4; ++j) bfr[j] = *(const bh8*)(Bs[p] + b_off[j]);
#pragma unroll
    for (int i = 0; i < 2; ++i) af[i] = *(const bh8*)(As[p] + a_off[i]);
#pragma unroll
    for (int i = 0; i < 2; ++i)
#pragma unroll
      for (int j = 0; j < 4; ++j)
        acc[i][j] = __builtin_amdgcn_mfma_f32_16x16x32_bf16(af[i], bfr[j], acc[i][j], 0, 0, 0);
    // write B(kt+1) from prefetched regs
    if (kt + 1 < NK) {
      bh8 w;
#pragma unroll
      for (int u = 0; u < 8; ++u) w[u] = (bh)rb[(kt + 1) & 1][u];
      *(bh8*)(Bs[1 - p] + b_wro) = w;
    }
    __syncthreads();
    // prefetch kt+2
    if (kt + 2 < NK) {
      const size_t ko = (size_t)(kt + 2) * 32;
#pragma unroll
      for (int i = 0; i < 8; ++i) rb[p][i] = bp[(ko + i) * 2048];
#pragma unroll
      for (int r = 0; r < 2; ++r)
        gload16(a_src[r] + ko, (char*)As[p] + a_dsto[r]);
    }
  }

  int nrows = ne - mt * 128; if (nrows > 128) nrows = 128;
  int jn[4]; float b1v[4];
#pragma unroll
  for (int j = 0; j < 4; ++j) {
    jn[j] = nt * 64 + j * 16 + ln15;
    b1v[j] = b1[e * 2048 + jn[j]];
  }
  const int rowbase = (int)offs[e] + mt * 128;
#pragma unroll
  for (int i = 0; i < 2; ++i)
#pragma unroll
    for (int rr = 0; rr < 4; ++rr) {
      int ml = wv * 32 + i * 16 + q * 4 + rr;
      if (ml < nrows) {
        size_t ro = (size_t)(rowbase + ml) * 2048;
#pragma unroll
        for (int j = 0; j < 4; ++j) {
          float vv = acc[i][j][rr] + b1v[j];
          hbf[ro + jn[j]] = (bh)fmaxf(vv, 0.f);
        }
      }
    }
}

// ---------------- GEMM2: y += gate * exp(h @ W2[e] + b2[e]) ----------------
__global__ __launch_bounds__(256, 2) void k_gemm2p(
    const bh* __restrict__ hbf, const float* __restrict__ W2,
    const float* __restrict__ b2, const int* __restrict__ tok_buck,
    const float* __restrict__ gate_buck, const unsigned* __restrict__ cnt,
    const unsigned* __restrict__ offs, float* __restrict__ yv) {
  const int e = blockIdx.z, mt = blockIdx.y, nt = blockIdx.x;
  const int ne = (int)cnt[e];
  if (mt * 128 >= ne) return;
  __shared__ __align__(16) bh As[2][128 * 32];
  __shared__ __align__(16) bh Bs[2][64 * 32];
  const int tid = threadIdx.x;
  const int lane = tid & 63, wv = tid >> 6;
  const int NK = 64;  // K=2048 / 32
  int nrows = ne - mt * 128; if (nrows > 128) nrows = 128;
  const int rowbase = (int)offs[e] + mt * 128;

  const bh* a_src[2]; int a_dsto[2];
#pragma unroll
  for (int r = 0; r < 2; ++r) {
    int task = r * 256 + tid;
    int row = task >> 2, s = task & 3;
    int gr = row; if (gr >= nrows) gr = nrows - 1;
    a_src[r] = hbf + (size_t)(rowbase + gr) * 2048 + ((s ^ swz(row)) << 3);
    a_dsto[r] = (r * 256 + (wv << 6)) * 16;
  }
  const int nl = tid & 63, kq = tid >> 6;
  const float* bp = W2 + (size_t)e * (2048 * 1024) + (size_t)(kq * 8) * 1024 +
                    nt * 64 + nl;
  const int b_wro = nl * 32 + ((kq ^ swz(nl)) << 3);

  const int ln15 = lane & 15, q = lane >> 4;
  int a_off[2], b_off[4];
#pragma unroll
  for (int i = 0; i < 2; ++i) {
    int row = wv * 32 + i * 16 + ln15;
    a_off[i] = row * 32 + ((q ^ swz(row)) << 3);
  }
#pragma unroll
  for (int j = 0; j < 4; ++j) {
    int row = j * 16 + ln15;
    b_off[j] = row * 32 + ((q ^ swz(row)) << 3);
  }
  fx4 zero = {0.f, 0.f, 0.f, 0.f};
  fx4 acc[2][4];
#pragma unroll
  for (int i = 0; i < 2; ++i)
#pragma unroll
    for (int j = 0; j < 4; ++j) acc[i][j] = zero;

  float rb[2][8];
#pragma unroll
  for (int i = 0; i < 8; ++i) rb[0][i] = bp[(size_t)i * 1024];
#pragma unroll
  for (int r = 0; r < 2; ++r) gload16(a_src[r], (char*)As[0] + a_dsto[r]);
  {
    bh8 w;
#pragma unroll
    for (int u = 0; u < 8; ++u) w[u] = (bh)rb[0][u];
    *(bh8*)(Bs[0] + b_wro) = w;
  }
#pragma unroll
  for (int i = 0; i < 8; ++i) rb[1][i] = bp[(size_t)(32 + i) * 1024];
#pragma unroll
  for (int r = 0; r < 2; ++r) gload16(a_src[r] + 32, (char*)As[1] + a_dsto[r]);
  __syncthreads();

  for (int kt = 0; kt < NK; ++kt) {
    const int p = kt & 1;
    bh8 bfr[4], af[2];
#pragma unroll
    for (int j = 0; j < 4; ++j) bfr[j] = *(const bh8*)(Bs[p] + b_off[j]);
#pragma unroll
    for (int i = 0; i < 2; ++i) af[i] = *(const bh8*)(As[p] + a_off[i]);
#pragma unroll
    for (int i = 0; i < 2; ++i)
#pragma unroll
      for (int j = 0; j < 4; ++j)
        acc[i][j] = __builtin_amdgcn_mfma_f32_16x16x32_bf16(af[i], bfr[j], acc[i][j], 0, 0, 0);
    if (kt + 1 < NK) {
      bh8 w;
#pragma unroll
      for (int u = 0; u < 8; ++u) w[u] = (bh)rb[(kt + 1) & 1][u];
      *(bh8*)(Bs[1 - p] + b_wro) = w;
    }
    __syncthreads();
    if (kt + 2 < NK) {
      const size_t ko = (size_t)(kt + 2) * 32;
#pragma unroll
      for (int i = 0; i < 8; ++i) rb[p][i] = bp[(ko + i) * 1024];
#pragma unroll
      for (int r = 0; r < 2; ++r)
        gload16(a_src[r] + ko, (char*)As[p] + a_dsto[r]);
    }
  }

  int on[4]; float b2v[4];
#pragma unroll
  for (int j = 0; j < 4; ++j) {
    on[j] = nt * 64 + j * 16 + ln15;
    b2v[j] = b2[e * 1024 + on[j]];
  }
#pragma unroll
  for (int i = 0; i < 2; ++i)
#pragma unroll
    for (int rr = 0; rr < 4; ++rr) {
      int ml = wv * 32 + i * 16 + q * 4 + rr;
      if (ml < nrows) {
        int pos = mt * 128 + ml;
        int bt = tok_buck[e * 1024 + pos];
        float gg = gate_buck[e * 1024 + pos];
        float* yrow = yv + (size_t)bt * 1024;
#pragma unroll
        for (int j = 0; j < 4; ++j)
          atomicAdd(&yrow[on[j]], gg * expf(acc[i][j][rr] + b2v[j]));
      }
    }
}

// ---------------- final log ----------------
__global__ __launch_bounds__(256) void k_log(float* __restrict__ yv) {
  const int i = blockIdx.x * 256 + threadIdx.x;
  fx4* p = (fx4*)yv + i;
  fx4 v = *p;
#pragma unroll
  for (int c = 0; c < 4; ++c) {
    float w = v[c];
    if (w == 0.f) w = 2.2204460492503131e-16f;
    v[c] = logf(w);
  }
  *p = v;
}

extern "C" void kernel_launch(void* const* d_in, const int* in_sizes, int n_in,
                              void* d_out, int out_size, void* d_ws, size_t ws_size,
                              hipStream_t stream) {
  const float* x  = (const float*)d_in[0];
  const float* wg = (const float*)d_in[1];
  const float* wn = (const float*)d_in[2];
  const float* W1 = (const float*)d_in[3];
  const float* b1 = (const float*)d_in[4];
  const float* W2 = (const float*)d_in[5];
  const float* b2 = (const float*)d_in[6];
  const float* nz = (const float*)d_in[7];
  float* out = (float*)d_out;

  char* ws = (char*)d_ws;
  unsigned* cnt      = (unsigned*)(ws + 0);            // 64 B
  unsigned* offs     = (unsigned*)(ws + 64);           // 64 B
  float*    imp_part = (float*)(ws + 256);             // 64 KB
  float*    load_part= (float*)(ws + 256 + 65536);     // 64 KB
  int*      tok_buck = (int*)(ws + 256 + 2 * 65536);   // 64 KB
  float*    gate_buck= (float*)(ws + 256 + 3 * 65536); // 64 KB
  bh*       xbf      = (bh*)(ws + 262400);             // 2 MiB
  bh*       hbf      = (bh*)(ws + 2359552);            // 4096*2048*2 = 16 MiB
  const size_t needed = 2359552 + (size_t)4096 * 2048 * 2;
  if (ws_size < needed) {
    hipMemsetAsync(d_out, 0x42, (size_t)out_size * 4, stream);  // sentinel
    return;
  }

  hipMemsetAsync(d_out, 0, (size_t)out_size * 4, stream);
  hipMemsetAsync(cnt, 0, 64, stream);

  k_gating<<<1024, 256, 0, stream>>>(x, wg, wn, nz, xbf, cnt, tok_buck, gate_buck,
                                     imp_part, load_part);
  k_finalize<<<1, 256, 0, stream>>>(cnt, offs, imp_part, load_part, out + (out_size - 1));
  // N-tile 64: gemm1 nt=2048/64=32, gemm2 nt=1024/64=16; mt up to 8 (128 rows each)
  k_gemm1p<<<dim3(32, 8, 16), 256, 0, stream>>>(xbf, W1, b1, tok_buck, cnt, offs, hbf);
  k_gemm2p<<<dim3(16, 8, 16), 256, 0, stream>>>(hbf, W2, b2, tok_buck, gate_buck, cnt, offs, out);
  k_log<<<1024, 256, 0, stream>>>(out);
}